// Round 15
// baseline (380.565 us; speedup 1.0000x reference)
//
#include <hip/hip_runtime.h>

#define BATCH 2048

// block-wide f32 sum; all threads get the result. red >= 32 floats.
__device__ __forceinline__ float blockReduceSumF(float v, float* red, int tid, int nwaves) {
  #pragma unroll
  for (int off = 32; off > 0; off >>= 1) v += __shfl_xor(v, off);
  __syncthreads();
  if ((tid & 63) == 0) red[tid >> 6] = v;
  __syncthreads();
  if (tid == 0) {
    float s = red[0];
    for (int i = 1; i < nwaves; i++) s += red[i];
    red[31] = s;
  }
  __syncthreads();
  return red[31];
}

// packed 2-value block reduce; per-component order identical to two sequential calls.
__device__ __forceinline__ float2 blockReduceSum2F(float a, float b, float* red, int tid, int nwaves) {
  #pragma unroll
  for (int off = 32; off > 0; off >>= 1) { a += __shfl_xor(a, off); b += __shfl_xor(b, off); }
  __syncthreads();
  if ((tid & 63) == 0) { red[tid >> 6] = a; red[(tid >> 6) + 16] = b; }
  __syncthreads();
  if (tid == 0) {
    float sa = red[0], sb = red[16];
    for (int i = 1; i < nwaves; i++) { sa += red[i]; sb += red[16 + i]; }
    red[30] = sa; red[31] = sb;
  }
  __syncthreads();
  return make_float2(red[30], red[31]);
}

// 2-wave (128-thread) group reduce; seg2 = 2-float LDS segment for this group.
// All 1024 threads of the block must call (uniform barriers).
__device__ __forceinline__ float groupReduce2w(float v, float* seg2, int tj) {
  #pragma unroll
  for (int off = 32; off > 0; off >>= 1) v += __shfl_xor(v, off);
  __syncthreads();
  if ((tj & 63) == 0) seg2[tj >> 6] = v;
  __syncthreads();
  return seg2[0] + seg2[1];
}

// ---------------- K0a: transpose conv2 weights -> w2t[cc][k][c2] (200 KB) ----------------
__global__ void k0_w2t(const float* __restrict__ w2, float* __restrict__ w2t) {
  int i = blockIdx.x * 256 + threadIdx.x;  // over 51200
  if (i >= 51200) return;
  int c2 = i / 800;
  int r = i - c2 * 800;           // cc*25 + k
  w2t[r * 64 + c2] = w2[i];
}

// ---------------- K1: conv1 + ternarize -> sign map + alpha1 (f32) — R14 verbatim ----
__global__ __launch_bounds__(512, 6) void k1_conv1(
    const float* __restrict__ x, const float* __restrict__ w1, const float* __restrict__ b1,
    signed char* __restrict__ s1full, float* __restrict__ alpha1) {
  __shared__ float xs[784];
  __shared__ float wsm[800];
  __shared__ float red[32];

  const int tid = threadIdx.x;
  const int smp = blockIdx.x;

  for (int j = tid; j < 784; j += 512) xs[j] = x[smp * 784 + j];
  for (int j = tid; j < 800; j += 512) wsm[j] = w1[j];
  __syncthreads();

  const int c = tid >> 4;
  const int g = tid & 15;
  const float bias = b1[c];
  const float* wc = &wsm[c * 25];

  float a[36];
  float asum = 0.0f;
  #pragma unroll
  for (int tt = 0; tt < 3; tt++) {
    const int t = g + (tt << 4);
    const int r = t >> 1;
    const int hx = (t & 1) * 12;
    float acc[12];
    #pragma unroll
    for (int i = 0; i < 12; i++) acc[i] = bias;
    #pragma unroll
    for (int ky = 0; ky < 5; ky++) {
      const float* xp = &xs[(r + ky) * 28 + hx];
      float xrow[16];
      *(float4*)&xrow[0]  = *(const float4*)&xp[0];
      *(float4*)&xrow[4]  = *(const float4*)&xp[4];
      *(float4*)&xrow[8]  = *(const float4*)&xp[8];
      *(float4*)&xrow[12] = *(const float4*)&xp[12];
      #pragma unroll
      for (int kx = 0; kx < 5; kx++) {
        const float w = wc[ky * 5 + kx];
        #pragma unroll
        for (int i = 0; i < 12; i++) acc[i] = fmaf(xrow[i + kx], w, acc[i]);
      }
    }
    #pragma unroll
    for (int i = 0; i < 12; i++) { a[tt * 12 + i] = acc[i]; asum += fabsf(acc[i]); }
  }

  float tot = blockReduceSumF(asum, red, tid, 8);
  float delta = (0.7f * tot) / 18432.0f;

  float msum = 0.0f, mcnt = 0.0f;
  #pragma unroll
  for (int i = 0; i < 36; i++) {
    float fa = fabsf(a[i]);
    if (fa > delta) { msum += fa; mcnt += 1.0f; }
  }
  float2 mm = blockReduceSum2F(msum, mcnt, red, tid, 8);
  if (tid == 0) alpha1[smp] = (mm.y > 0.0f) ? (mm.x / mm.y) : 0.0f;

  signed char* sp = s1full + (size_t)smp * 18432 + c * 576 + g * 12;
  #pragma unroll
  for (int tt = 0; tt < 3; tt++) {
    #pragma unroll
    for (int i = 0; i < 12; i++) {
      float v = a[tt * 12 + i];
      int sv = (v > delta) ? 1 : ((v < -delta) ? -1 : 0);
      sp[tt * 192 + i] = (signed char)sv;
    }
  }
}

// ---------------- K2: BN1+maxpool+relu, conv2, ternarize — R14 verbatim ----
__global__ __launch_bounds__(256, 6) void k2_conv2(
    const signed char* __restrict__ s1full, const float* __restrict__ alpha1,
    const float* __restrict__ w2t, const float* __restrict__ b2,
    const float* __restrict__ g1, const float* __restrict__ bt1,
    signed char* __restrict__ s2full, float* __restrict__ alpha2) {
  __shared__ float pooled[4608];
  __shared__ float g1l[32], bt1l[32];
  __shared__ float red[32];

  const int tid = threadIdx.x;
  const int smp = blockIdx.x;
  const float BNINV = (float)(1.0 / sqrt(1.0 + 1e-5));

  if (tid < 32) { g1l[tid] = g1[tid] * BNINV; bt1l[tid] = bt1[tid]; }
  __syncthreads();

  const float a1 = alpha1[smp];
  for (int j = tid; j < 4608; j += 256) {
    int cc = j / 144;
    int r = j - cc * 144;
    int py = r / 12;
    int px = r - py * 12;
    const signed char* sp = s1full + (size_t)smp * 18432 + cc * 576 + (py * 2) * 24 + px * 2;
    float m = -1e30f;
    #pragma unroll
    for (int dy = 0; dy < 2; dy++)
      #pragma unroll
      for (int dx = 0; dx < 2; dx++) {
        float v = ((float)sp[dy * 24 + dx] * a1) * g1l[cc] + bt1l[cc];
        m = (v > m) ? v : m;
      }
    pooled[j] = (m > 0.0f) ? m : 0.0f;
  }
  __syncthreads();

  const int c2 = tid >> 2;
  const int q = tid & 3;
  const int r0 = q << 1;
  const float bias = b2[c2];
  float acc0[8], acc1[8];
  #pragma unroll
  for (int i = 0; i < 8; i++) { acc0[i] = bias; acc1[i] = bias; }

  for (int cc = 0; cc < 32; cc++) {
    const float* wt = w2t + cc * 1600 + c2;
    const float* pb = &pooled[cc * 144];
    float rows[2][12];
    *(float4*)&rows[0][0] = *(const float4*)&pb[r0 * 12];
    *(float4*)&rows[0][4] = *(const float4*)&pb[r0 * 12 + 4];
    *(float4*)&rows[0][8] = *(const float4*)&pb[r0 * 12 + 8];
    #pragma unroll
    for (int ky = 0; ky < 5; ky++) {
      float* B = rows[(ky + 1) & 1];
      const float* bp = &pb[(r0 + ky + 1) * 12];
      *(float4*)&B[0] = *(const float4*)&bp[0];
      *(float4*)&B[4] = *(const float4*)&bp[4];
      *(float4*)&B[8] = *(const float4*)&bp[8];
      const float* A = rows[ky & 1];
      #pragma unroll
      for (int kx = 0; kx < 5; kx++) {
        const float w = wt[(ky * 5 + kx) << 6];
        #pragma unroll
        for (int ox = 0; ox < 8; ox++) acc0[ox] = fmaf(A[ox + kx], w, acc0[ox]);
        #pragma unroll
        for (int ox = 0; ox < 8; ox++) acc1[ox] = fmaf(B[ox + kx], w, acc1[ox]);
      }
    }
  }

  float asum = 0.0f;
  #pragma unroll
  for (int i = 0; i < 8; i++) asum += fabsf(acc0[i]) + fabsf(acc1[i]);
  float tot = blockReduceSumF(asum, red, tid, 4);
  float delta = (0.7f * tot) / 4096.0f;

  float msum = 0.0f, mcnt = 0.0f;
  #pragma unroll
  for (int i = 0; i < 8; i++) {
    float f0 = fabsf(acc0[i]);
    if (f0 > delta) { msum += f0; mcnt += 1.0f; }
    float f1 = fabsf(acc1[i]);
    if (f1 > delta) { msum += f1; mcnt += 1.0f; }
  }
  float2 mm = blockReduceSum2F(msum, mcnt, red, tid, 4);
  if (tid == 0) alpha2[smp] = (mm.y > 0.0f) ? (mm.x / mm.y) : 0.0f;

  signed char* so = s2full + (size_t)smp * 4096 + c2 * 64 + r0 * 8;
  #pragma unroll
  for (int ox = 0; ox < 8; ox++) {
    float v = acc0[ox];
    so[ox] = (signed char)((v > delta) ? 1 : ((v < -delta) ? -1 : 0));
  }
  #pragma unroll
  for (int ox = 0; ox < 8; ox++) {
    float v = acc1[ox];
    so[8 + ox] = (signed char)((v > delta) ? 1 : ((v < -delta) ? -1 : 0));
  }
}

// ---------------- K0t: transpose fc1 weights into w1t[k][o] (into dead s1full) ----------
__global__ void k0_transpose(const float* __restrict__ w1f, float* __restrict__ w1t) {
  int i = blockIdx.x * 256 + threadIdx.x;  // i over 524288
  int k = i >> 9;
  int o = i & 511;
  w1t[i] = w1f[o * 1024 + k];
}

// ---------------- K3 v2: 8 samples/block (grid 256) — halves fc1 L2 weight traffic.
// fc1 partial arithmetic and kp-ascending+bias-last reduction bit-identical to R13. ----
__global__ __launch_bounds__(1024, 4) void k3_fc8(
    const signed char* __restrict__ s2full, const float* __restrict__ alpha2,
    const float* __restrict__ w1t, const float* __restrict__ f1b,
    const float* __restrict__ w2f, const float* __restrict__ f2b,
    const float* __restrict__ g2, const float* __restrict__ bt2,
    float* __restrict__ out) {
  __shared__ float S[8192];        // phase1-2: h4[j][s] (32 KB); phase3+: h3[8][512]
  __shared__ float fco[8][512];    // 16 KB
  __shared__ float g2l[64], bt2l[64];
  __shared__ float seg[8][2];
  __shared__ float out2[8][10];

  const int tid = threadIdx.x;
  const int blk = blockIdx.x;  // samples blk*8 .. blk*8+7
  const float BNINV = (float)(1.0 / sqrt(1.0 + 1e-5));

  if (tid < 64) { g2l[tid] = g2[tid] * BNINV; bt2l[tid] = bt2[tid]; }
  // zero fco while h4 is being built (disjoint arrays)
  for (int p = tid; p < 4096; p += 1024) ((float*)fco)[p] = 0.0f;
  __syncthreads();

  // phase 1: h4[j][s] (literal BN+maxpool+relu), 8192 elements
  for (int e = tid; e < 8192; e += 1024) {
    int j = e >> 3;
    int s = e & 7;
    int cc = j >> 4;
    int r = j & 15;
    int py = r >> 2;
    int px = r & 3;
    const signed char* sp = s2full + (size_t)(blk * 8 + s) * 4096 + cc * 64 + (py * 2) * 8 + px * 2;
    float a2 = alpha2[blk * 8 + s];
    float m = -1e30f;
    #pragma unroll
    for (int dy = 0; dy < 2; dy++)
      #pragma unroll
      for (int dx = 0; dx < 2; dx++) {
        float v = ((float)sp[dy * 8 + dx] * a2) * g2l[cc] + bt2l[cc];
        m = (v > m) ? v : m;
      }
    S[j * 8 + s] = (m > 0.0f) ? m : 0.0f;
  }
  __syncthreads();

  // phase 2: fc1 partials. thread = kp (tid>>7) x og (tid&127); 4 outputs x 8 samples.
  const int kp = tid >> 7;
  const int og = tid & 127;
  float ac[8][4];
  #pragma unroll
  for (int s = 0; s < 8; s++)
    #pragma unroll
    for (int i = 0; i < 4; i++) ac[s][i] = 0.0f;

  {
    const float4* w4 = (const float4*)w1t;
    const float4* h84 = (const float4*)S;
    const int kbase = kp << 7;
    for (int kk = 0; kk < 128; kk++) {
      const int k = kbase + kk;
      const float4 wv = w4[(k << 7) + og];
      const float4 h0 = h84[2 * k];      // h[k][0..3] (broadcast)
      const float4 h1 = h84[2 * k + 1];  // h[k][4..7]
      float hs[8] = {h0.x, h0.y, h0.z, h0.w, h1.x, h1.y, h1.z, h1.w};
      #pragma unroll
      for (int s = 0; s < 8; s++) {
        ac[s][0] = fmaf(hs[s], wv.x, ac[s][0]);
        ac[s][1] = fmaf(hs[s], wv.y, ac[s][1]);
        ac[s][2] = fmaf(hs[s], wv.z, ac[s][2]);
        ac[s][3] = fmaf(hs[s], wv.w, ac[s][3]);
      }
    }
  }

  // kp-ascending sequential accumulate into fco (bit-identical order to R13's reduce)
  #pragma unroll 1
  for (int j = 0; j < 8; j++) {
    if (kp == j) {
      #pragma unroll
      for (int s = 0; s < 8; s++)
        #pragma unroll
        for (int i = 0; i < 4; i++)
          fco[s][og * 4 + i] += ac[s][i];
    }
    __syncthreads();
  }
  // bias last (as R13)
  for (int p = tid; p < 4096; p += 1024) {
    int s = p >> 9;
    int o = p & 511;
    fco[s][o] += f1b[o];
  }
  __syncthreads();

  // phase 3: per-sample ternarize+relu (8 groups of 128 threads = 2 waves)
  float (*h3)[512] = (float(*)[512])S;  // h4 dead (all phase-2 reads barriered above)
  const int sg = tid >> 7;
  const int tj = tid & 127;
  float v[4], av[4];
  #pragma unroll
  for (int i = 0; i < 4; i++) { v[i] = fco[sg][tj + (i << 7)]; av[i] = fabsf(v[i]); }
  float tot = groupReduce2w(((av[0] + av[1]) + (av[2] + av[3])), seg[sg], tj);
  float delta = (0.7f * tot) / 512.0f;
  float msum = 0.0f, mcnt = 0.0f;
  #pragma unroll
  for (int i = 0; i < 4; i++) {
    if (av[i] > delta) { msum += av[i]; mcnt += 1.0f; }
  }
  msum = groupReduce2w(msum, seg[sg], tj);
  mcnt = groupReduce2w(mcnt, seg[sg], tj);
  float alpha3 = (mcnt > 0.0f) ? (msum / mcnt) : 0.0f;
  #pragma unroll
  for (int i = 0; i < 4; i++) {
    float t = (v[i] > delta) ? 1.0f : ((v[i] < -delta) ? -1.0f : 0.0f);
    float hv = t * alpha3;
    h3[sg][tj + (i << 7)] = (hv > 0.0f) ? hv : 0.0f;
  }
  __syncthreads();

  // phase 4: fc2 — 80 (sample, output) tasks over 16 waves
  const int lane = tid & 63;
  const int wid = tid >> 6;
  for (int t = wid; t < 80; t += 16) {
    int s = t / 10;
    int o = t - s * 10;
    float acc = 0.0f;
    #pragma unroll
    for (int m = 0; m < 8; m++) {
      int j = lane + (m << 6);
      acc = fmaf(h3[s][j], w2f[o * 512 + j], acc);
    }
    #pragma unroll
    for (int off = 32; off > 0; off >>= 1) acc += __shfl_xor(acc, off);
    if (lane == 0) out2[s][o] = acc + f2b[o];
  }
  __syncthreads();

  // phase 5: final ternarize per sample -> float out
  if (tid < 8) {
    int s = tid;
    float t2 = 0.0f;
    for (int i = 0; i < 10; i++) t2 += fabsf(out2[s][i]);
    float d = (0.7f * t2) / 10.0f;
    float ms = 0.0f, mc = 0.0f;
    for (int i = 0; i < 10; i++) {
      float a = fabsf(out2[s][i]);
      if (a > d) { ms += a; mc += 1.0f; }
    }
    float al = (mc > 0.0f) ? (ms / mc) : 0.0f;
    for (int i = 0; i < 10; i++) {
      float vv = out2[s][i];
      float sv = (vv > d) ? 1.0f : ((vv < -d) ? -1.0f : 0.0f);
      out[(size_t)(blk * 8 + s) * 10 + i] = sv * al;
    }
  }
}

// assumption-violation marker
__global__ void k_marker(float* __restrict__ out, int n, float val) {
  int i = blockIdx.x * 256 + threadIdx.x;
  if (i < n) out[i] = val;
}

extern "C" void kernel_launch(void* const* d_in, const int* in_sizes, int n_in,
                              void* d_out, int out_size, void* d_ws, size_t ws_size,
                              hipStream_t stream) {
  float* out = (float*)d_out;

  static const int expect[13] = {1605632, 800, 32, 32, 32, 51200, 64, 64, 64,
                                 524288, 512, 5120, 10};
  float marker = 0.0f;
  if (n_in != 13) marker = 304.0f;
  else {
    for (int i = 0; i < 13; i++)
      if (in_sizes[i] != expect[i]) { marker = 320.0f + 16.0f * i; break; }
  }
  if (marker == 0.0f && out_size != 20480) marker = 560.0f;

  float* alpha1 = (float*)d_ws;                           // 2048
  float* alpha2 = alpha1 + BATCH;                         // 2048
  float* w2t    = alpha2 + BATCH;                         // 51200 (200 KB)
  signed char* s1full = (signed char*)(w2t + 51200);      // 2048*18432 (dead after k2;
                                                          //  first 2MB reused as w1t)
  signed char* s2full = s1full + (size_t)BATCH * 18432;   // 2048*4096
  size_t needed = (size_t)((s2full + (size_t)BATCH * 4096) - (signed char*)d_ws);
  if (marker == 0.0f && ws_size < needed) marker = 576.0f;

  if (marker != 0.0f) {
    k_marker<<<dim3((out_size + 255) / 256), dim3(256), 0, stream>>>(out, out_size, marker);
    return;
  }

  const float* x   = (const float*)d_in[0];
  const float* c1w = (const float*)d_in[1];
  const float* c1b = (const float*)d_in[2];
  const float* g1  = (const float*)d_in[3];
  const float* bt1 = (const float*)d_in[4];
  const float* c2w = (const float*)d_in[5];
  const float* c2b = (const float*)d_in[6];
  const float* g2  = (const float*)d_in[7];
  const float* bt2 = (const float*)d_in[8];
  const float* f1w = (const float*)d_in[9];
  const float* f1b = (const float*)d_in[10];
  const float* f2w = (const float*)d_in[11];
  const float* f2b = (const float*)d_in[12];

  float* w1t = (float*)s1full;

  k0_w2t<<<dim3(200), dim3(256), 0, stream>>>(c2w, w2t);
  k1_conv1<<<dim3(BATCH), dim3(512), 0, stream>>>(x, c1w, c1b, s1full, alpha1);
  k2_conv2<<<dim3(BATCH), dim3(256), 0, stream>>>(s1full, alpha1, w2t, c2b, g1, bt1, s2full, alpha2);
  k0_transpose<<<dim3(2048), dim3(256), 0, stream>>>(f1w, w1t);
  k3_fc8<<<dim3(BATCH / 8), dim3(1024), 0, stream>>>(s2full, alpha2, w1t, f1b, f2w, f2b, g2, bt2, out);
}